// Round 1
// baseline (149.735 us; speedup 1.0000x reference)
//
#include <hip/hip_runtime.h>

// Moreau-tropical forward.
// For each (b,n): z = x[b] + W[n] (D=1024). Root of f(tau)=sum relu(z-tau)=lam,
// then y = tau + sum relu(z-tau)^2 / (2 lam).
//
// Key fact: f(M - lam) >= lam where M = max(z)  (max element alone contributes lam),
// so the root lies in [M-lam, M] and ONLY elements with z > M-lam ever matter.
// We compress those candidates (typically 1-8 of 1024) to one-per-lane and bisect
// on them. y is 2nd-order insensitive to tau error (dy/dtau = 0 at root), so 20
// bisection steps on a width-lam interval match the reference's 32 steps on the
// wide interval to ~1e-12.

#define D_DIM 1024
#define WAVES_PER_BLOCK 4
#define CAP 64      // candidates capacity = 1 per lane
#define NB_CAND 20  // bisection iters, candidate path
#define NB_FULL 24  // bisection iters, (never-taken-in-practice) fallback path

__device__ __forceinline__ float wave_sum(float v) {
#pragma unroll
    for (int m = 1; m < 64; m <<= 1) v += __shfl_xor(v, m, 64);
    return v;
}
__device__ __forceinline__ float wave_max(float v) {
#pragma unroll
    for (int m = 1; m < 64; m <<= 1) v = fmaxf(v, __shfl_xor(v, m, 64));
    return v;
}

__global__ void __launch_bounds__(WAVES_PER_BLOCK * 64)
moreau_tropical(const float* __restrict__ x, const float* __restrict__ W,
                const float* __restrict__ lam_p, float* __restrict__ out, int N) {
    __shared__ float s_cand[WAVES_PER_BLOCK][CAP];
    __shared__ int s_cnt[WAVES_PER_BLOCK];

    const int lane = threadIdx.x & 63;
    const int w    = threadIdx.x >> 6;
    const int b    = blockIdx.y;
    int n = blockIdx.x * WAVES_PER_BLOCK + w;
    if (n >= N) n = N - 1;  // duplicate work; duplicate store of identical value is benign

    const float lam = lam_p[0];

    const float4* xrow = (const float4*)(x + (size_t)b * D_DIM);
    const float4* wrow = (const float4*)(W + (size_t)n * D_DIM);

    // z in registers: lane handles d = 256*j + 4*lane + {0..3}  (coalesced float4 loads)
    float4 zv[4];
    float mloc = -3.0e38f;
#pragma unroll
    for (int j = 0; j < 4; ++j) {
        float4 a = xrow[j * 64 + lane];
        float4 c = wrow[j * 64 + lane];
        float4 z;
        z.x = a.x + c.x; z.y = a.y + c.y; z.z = a.z + c.z; z.w = a.w + c.w;
        zv[j] = z;
        mloc = fmaxf(mloc, fmaxf(fmaxf(z.x, z.y), fmaxf(z.z, z.w)));
    }
    const float M   = wave_max(mloc);
    const float thr = M - lam;   // root is in [thr, M]; only z > thr matters

    if (lane == 0) s_cnt[w] = 0;
    __syncthreads();

    // compress candidates (z > thr) into LDS, one wave-segment each
#pragma unroll
    for (int j = 0; j < 4; ++j) {
        float zz[4] = {zv[j].x, zv[j].y, zv[j].z, zv[j].w};
#pragma unroll
        for (int c = 0; c < 4; ++c) {
            if (zz[c] > thr) {
                int idx = atomicAdd(&s_cnt[w], 1);
                if (idx < CAP) s_cand[w][idx] = zz[c];
            }
        }
    }
    __syncthreads();

    const int total = s_cnt[w];
    float lo = thr, hi = M, tau, delta;

    if (total <= CAP) {  // wave-uniform branch; always taken for Gaussian-like data
        const float cand = (lane < total) ? s_cand[w][lane] : -3.0e38f;
#pragma unroll
        for (int t = 0; t < NB_CAND; ++t) {
            const float mid = 0.5f * (lo + hi);
            const float f   = wave_sum(fmaxf(cand - mid, 0.0f));
            const bool too_low = f > lam;
            lo = too_low ? mid : lo;
            hi = too_low ? hi : mid;
        }
        tau = 0.5f * (lo + hi);
        const float s = fmaxf(cand - tau, 0.0f);
        delta = wave_sum(s * s) / (2.0f * lam);
    } else {
        // fallback: full-register bisection on the same (still valid) interval
        for (int t = 0; t < NB_FULL; ++t) {
            const float mid = 0.5f * (lo + hi);
            float fl = 0.0f;
#pragma unroll
            for (int j = 0; j < 4; ++j) {
                fl += fmaxf(zv[j].x - mid, 0.0f);
                fl += fmaxf(zv[j].y - mid, 0.0f);
                fl += fmaxf(zv[j].z - mid, 0.0f);
                fl += fmaxf(zv[j].w - mid, 0.0f);
            }
            const float f = wave_sum(fl);
            const bool too_low = f > lam;
            lo = too_low ? mid : lo;
            hi = too_low ? hi : mid;
        }
        tau = 0.5f * (lo + hi);
        float dl = 0.0f;
#pragma unroll
        for (int j = 0; j < 4; ++j) {
            float sx = fmaxf(zv[j].x - tau, 0.0f); dl += sx * sx;
            float sy = fmaxf(zv[j].y - tau, 0.0f); dl += sy * sy;
            float sz = fmaxf(zv[j].z - tau, 0.0f); dl += sz * sz;
            float sw = fmaxf(zv[j].w - tau, 0.0f); dl += sw * sw;
        }
        delta = wave_sum(dl) / (2.0f * lam);
    }

    if (lane == 0) out[(size_t)b * N + n] = tau + delta;
}

extern "C" void kernel_launch(void* const* d_in, const int* in_sizes, int n_in,
                              void* d_out, int out_size, void* d_ws, size_t ws_size,
                              hipStream_t stream) {
    const float* x    = (const float*)d_in[0];
    const float* W    = (const float*)d_in[1];
    const float* lamp = (const float*)d_in[2];
    float* out        = (float*)d_out;

    const int B = in_sizes[0] / D_DIM;
    const int N = in_sizes[1] / D_DIM;

    dim3 grid((N + WAVES_PER_BLOCK - 1) / WAVES_PER_BLOCK, B);
    moreau_tropical<<<grid, WAVES_PER_BLOCK * 64, 0, stream>>>(x, W, lamp, out, N);
}